// Round 4
// baseline (167047.217 us; speedup 1.0000x reference)
//
#include <hip/hip_runtime.h>
#include <cstdint>

// Problem constants (from reference): I=256, H=1024, O=1, T=16384
#define I_DIM   256
#define H_DIM   1024
#define T_STEPS 16384
#define NBLK    128     // persistent blocks, 1 per CU (256 CUs -> 2x residency margin)
#define CELLS   8       // h cells per block  (128*8 = 1024)
#define THREADS 512     // 8 waves; wave wv owns cell wv; 16-lane group = gate

// Fast device math: v_exp_f32 / v_rcp_f32 based, ~1-2 ulp.
__device__ __forceinline__ float fast_sigmoid(float x) {
    return __builtin_amdgcn_rcpf(1.f + __expf(-x));
}
__device__ __forceinline__ float fast_tanh(float x) {
    const float a = fabsf(x);
    const float e = __expf(-2.f * a);
    const float t = (1.f - e) * __builtin_amdgcn_rcpf(1.f + e);
    return copysignf(t, x);
}

// ---------------------------------------------------------------------------
// Persistent LSTM scan, fully barrier-free dataflow:
//  - global: 2-slot ring of (tag<<32|float_bits) u64, relaxed-load poll,
//    RELEASE publish (pinned by asm barrier) -- publish delay was R3's bug.
//  - intra-block: wave wv polls ONLY its 128 ring words, writes them to LDS,
//    release-stores flag[wv]=t; consumers acquire-spin per chunk in wrap
//    order and fold chunks into the dot as they arrive (pipelined tail).
//  - weights pre-PERMUTED into registers so the chunk loop uses only
//    compile-time register indices (no scratch).
// Reuse-safety (no __syncthreads in loop): wave W overwrites LDS slot s at
// step t only after its ring poll saw tag t-1, whose producers consumed
// h_{t-2} incl. this block's cells => local waves published t-2 => their
// step-(t-2) reads of slot s (h_{t-3}) are done. All deps are true data
// deps, so HW causality orders the LDS write after those reads.
// ---------------------------------------------------------------------------
__launch_bounds__(THREADS, 2)
__global__ void lstm_persist(const float* __restrict__ x,
                             const float* __restrict__ W_ih,
                             const float* __restrict__ W_hh,
                             const float* __restrict__ b_ih,
                             const float* __restrict__ b_hh,
                             unsigned long long* __restrict__ ring)
{
    __shared__ __align__(16) float hbuf[2][H_DIM];
    __shared__ int flagS[8];

    const int tid = threadIdx.x;
    const int blk = blockIdx.x;
    const int wv  = tid >> 6;           // wave id = cell within block (0..7)
    const int ln  = tid & 63;           // lane within wave
    const int q   = (tid >> 4) & 3;     // 16-lane group = gate (i,f,g,o)
    const int l   = tid & 15;           // lane within group
    const int row_g = q * H_DIM + blk * CELLS + wv;   // global gate row

    // --- W_hh row slice, PERMUTED by chunk: wB[jj] holds chunk c=(wv+jj)&7.
    //     Chunk c covers h[c*128 .. c*128+127]; lane l takes float4s at
    //     c*32 + l and c*32 + 16 + l.
    const float4* Wrow = reinterpret_cast<const float4*>(W_hh + (size_t)row_g * H_DIM);
    float4 wB[8][2];
    #pragma unroll
    for (int jj = 0; jj < 8; ++jj) {
        const int c = (wv + jj) & 7;
        wB[jj][0] = Wrow[c * 32 + l];
        wB[jj][1] = Wrow[c * 32 + 16 + l];
    }
    // --- W_ih row slice: lane l covers k = S*64 + l*4
    const float4* Vrow = reinterpret_cast<const float4*>(W_ih + (size_t)row_g * I_DIM);
    float4 wI0 = Vrow[0*16 + l], wI1 = Vrow[1*16 + l], wI2 = Vrow[2*16 + l], wI3 = Vrow[3*16 + l];
    const float bias_r = b_ih[row_g] + b_hh[row_g];

    // --- init: h_{-1}=0 in hbuf[1] (slot (0-1)&1), flags=0 ("step-0 input ready")
    *reinterpret_cast<float2*>(&hbuf[1][wv * 128 + 2 * ln]) = make_float2(0.f, 0.f);
    if (ln == 0) flagS[wv] = 0;
    __syncthreads();   // once, pre-loop

    // --- xg for t=0, straight from global x row 0
    float xg;
    {
        const float* xrow = x;
        const float4 xv0 = *reinterpret_cast<const float4*>(&xrow[0*64 + l*4]);
        const float4 xv1 = *reinterpret_cast<const float4*>(&xrow[1*64 + l*4]);
        const float4 xv2 = *reinterpret_cast<const float4*>(&xrow[2*64 + l*4]);
        const float4 xv3 = *reinterpret_cast<const float4*>(&xrow[3*64 + l*4]);
        xg = (l == 0) ? bias_r : 0.f;
        xg += wI0.x*xv0.x + wI0.y*xv0.y + wI0.z*xv0.z + wI0.w*xv0.w;
        xg += wI1.x*xv1.x + wI1.y*xv1.y + wI1.z*xv1.z + wI1.w*xv1.w;
        xg += wI2.x*xv2.x + wI2.y*xv2.y + wI2.z*xv2.z + wI2.w*xv2.w;
        xg += wI3.x*xv3.x + wI3.y*xv3.y + wI3.z*xv3.z + wI3.w*xv3.w;
    }

    float c_state = 0.f;    // cell state (replicated across the wave's 64 lanes)

    for (int t = 0; t < T_STEPS; ++t) {
        const int prev_slot = (t - 1) & 1;     // (-1)&1 == 1 for t=0
        float* hb = hbuf[prev_slot];

        // (1) owner: poll OWN 128 ring words for h_{t-1}, stage to LDS, flag.
        if (t >= 1) {
            const unsigned long long want = (unsigned long long)(t - 1);
            unsigned long long* p = ring + (prev_slot ? H_DIM : 0) + wv * 128 + 2 * ln;
            unsigned long long a, b;
            for (;;) {  // both loads in flight each iter: one vmcnt wait, no divergence
                a = __hip_atomic_load(p,     __ATOMIC_RELAXED, __HIP_MEMORY_SCOPE_AGENT);
                b = __hip_atomic_load(p + 1, __ATOMIC_RELAXED, __HIP_MEMORY_SCOPE_AGENT);
                if (((a >> 32) == want) & ((b >> 32) == want)) break;
            }
            float2 hv;
            hv.x = __uint_as_float((unsigned)a);
            hv.y = __uint_as_float((unsigned)b);
            *reinterpret_cast<float2*>(&hb[wv * 128 + 2 * ln]) = hv;
            if (ln == 0)
                __hip_atomic_store(&flagS[wv], t, __ATOMIC_RELEASE, __HIP_MEMORY_SCOPE_WORKGROUP);
        }

        // (2) chunk-pipelined recurrent dot: fold chunks as flags land.
        float acc = xg;
        #pragma unroll
        for (int jj = 0; jj < 8; ++jj) {
            const int c = (wv + jj) & 7;
            if (jj != 0) {
                while (__hip_atomic_load(&flagS[c], __ATOMIC_ACQUIRE,
                                         __HIP_MEMORY_SCOPE_WORKGROUP) != t) {}
            }
            const float4 ha = *reinterpret_cast<const float4*>(&hb[c * 128 + l * 4]);
            const float4 hc = *reinterpret_cast<const float4*>(&hb[c * 128 + 64 + l * 4]);
            acc += wB[jj][0].x*ha.x + wB[jj][0].y*ha.y + wB[jj][0].z*ha.z + wB[jj][0].w*ha.w;
            acc += wB[jj][1].x*hc.x + wB[jj][1].y*hc.y + wB[jj][1].z*hc.z + wB[jj][1].w*hc.w;
        }

        // (3) 16-lane butterfly -> row value; gather 4 gates in-wave
        acc += __shfl_xor(acc, 1);
        acc += __shfl_xor(acc, 2);
        acc += __shfl_xor(acc, 4);
        acc += __shfl_xor(acc, 8);
        const float gi_r = __shfl(acc, 0);
        const float gf_r = __shfl(acc, 16);
        const float gg_r = __shfl(acc, 32);
        const float go_r = __shfl(acc, 48);
        // (4) gates (fast math, redundant on all lanes)
        const float gi = fast_sigmoid(gi_r);
        const float gf = fast_sigmoid(gf_r);
        const float gg = fast_tanh(gg_r);
        const float go = fast_sigmoid(go_r);
        c_state = gf * c_state + gi * gg;
        const float h_new = go * fast_tanh(c_state);

        // (5) publish h_t FIRST -- release, pinned so nothing floats above/below it
        if (ln == 0) {
            const unsigned long long pack =
                ((unsigned long long)t << 32) | (unsigned long long)__float_as_uint(h_new);
            __hip_atomic_store(ring + ((t & 1) ? H_DIM : 0) + blk * CELLS + wv, pack,
                               __ATOMIC_RELEASE, __HIP_MEMORY_SCOPE_AGENT);
        }
        asm volatile("" ::: "memory");

        // (6) tail (off critical path): xg for t+1 straight from global
        {
            const int tt = (t + 1 < T_STEPS) ? t + 1 : T_STEPS - 1;
            const float* xrow = x + (size_t)tt * I_DIM;
            const float4 xv0 = *reinterpret_cast<const float4*>(&xrow[0*64 + l*4]);
            const float4 xv1 = *reinterpret_cast<const float4*>(&xrow[1*64 + l*4]);
            const float4 xv2 = *reinterpret_cast<const float4*>(&xrow[2*64 + l*4]);
            const float4 xv3 = *reinterpret_cast<const float4*>(&xrow[3*64 + l*4]);
            float xg_n = (l == 0) ? bias_r : 0.f;
            xg_n += wI0.x*xv0.x + wI0.y*xv0.y + wI0.z*xv0.z + wI0.w*xv0.w;
            xg_n += wI1.x*xv1.x + wI1.y*xv1.y + wI1.z*xv1.z + wI1.w*xv1.w;
            xg_n += wI2.x*xv2.x + wI2.y*xv2.y + wI2.z*xv2.z + wI2.w*xv2.w;
            xg_n += wI3.x*xv3.x + wI3.y*xv3.y + wI3.z*xv3.z + wI3.w*xv3.w;
            xg = xg_n;
        }
    }
}

// ---------------------------------------------------------------------------
// Final FFN: z = relu(h @ W1.T + b1);  partial_b = sum_j z_j * W2_j per block
// ---------------------------------------------------------------------------
__global__ void ffn_kernel(const unsigned long long* __restrict__ ring,
                           const float* __restrict__ W1,
                           const float* __restrict__ b1,
                           const float* __restrict__ W2,
                           float* __restrict__ partials)
{
    __shared__ float psum[8];
    const int tid = threadIdx.x;        // 256
    const int r2  = tid >> 5;           // 0..7
    const int l2  = tid & 31;
    const int j   = blockIdx.x * 8 + r2;
    const unsigned long long* hslot = ring + (((T_STEPS - 1) & 1) ? H_DIM : 0);

    float acc = 0.f;
    #pragma unroll 8
    for (int kk = 0; kk < 32; ++kk) {
        const int   k  = kk * 32 + l2;
        const float hk = __uint_as_float((unsigned)hslot[k]);
        acc += hk * W1[(size_t)j * H_DIM + k];
    }
    acc += __shfl_xor(acc, 1);
    acc += __shfl_xor(acc, 2);
    acc += __shfl_xor(acc, 4);
    acc += __shfl_xor(acc, 8);
    acc += __shfl_xor(acc, 16);
    if (l2 == 0) {
        float z = acc + b1[j];
        z = z > 0.f ? z : 0.f;
        psum[r2] = z * W2[j];
    }
    __syncthreads();
    if (tid == 0) {
        float s = 0.f;
        #pragma unroll
        for (int i = 0; i < 8; ++i) s += psum[i];
        partials[blockIdx.x] = s;
    }
}

__global__ void out_kernel(const float* __restrict__ partials,
                           const float* __restrict__ b2,
                           float* __restrict__ out)
{
    __shared__ float ws2[2];
    const int tid = threadIdx.x;        // 128
    float v = partials[tid];
    v += __shfl_xor(v, 1);
    v += __shfl_xor(v, 2);
    v += __shfl_xor(v, 4);
    v += __shfl_xor(v, 8);
    v += __shfl_xor(v, 16);
    v += __shfl_xor(v, 32);
    if ((tid & 63) == 0) ws2[tid >> 6] = v;
    __syncthreads();
    if (tid == 0) out[0] = ws2[0] + ws2[1] + b2[0];
}

extern "C" void kernel_launch(void* const* d_in, const int* in_sizes, int n_in,
                              void* d_out, int out_size, void* d_ws, size_t ws_size,
                              hipStream_t stream)
{
    const float* x    = (const float*)d_in[0];   // (1,T,I)
    const float* W_ih = (const float*)d_in[1];   // (4H,I)
    const float* W_hh = (const float*)d_in[2];   // (4H,H)
    const float* b_ih = (const float*)d_in[3];   // (4H)
    const float* b_hh = (const float*)d_in[4];   // (4H)
    const float* W1   = (const float*)d_in[5];   // (H,H)
    const float* b1   = (const float*)d_in[6];   // (H)
    const float* W2   = (const float*)d_in[7];   // (1,H)
    const float* b2   = (const float*)d_in[8];   // (1)
    float* out = (float*)d_out;

    unsigned long long* ring = (unsigned long long*)d_ws;         // 2*H u64 = 16 KiB
    const size_t ring_bytes = (size_t)2 * H_DIM * sizeof(unsigned long long);
    float* partials = (float*)((char*)d_ws + ring_bytes);         // 128 f32

    // Poison ring tags so stale tags from a previous replay can never match
    // (tag 0xAAAAAAAA != any step index). Harness also poisons ws to 0xAA.
    hipMemsetAsync(d_ws, 0xAA, ring_bytes, stream);

    lstm_persist<<<NBLK, THREADS, 0, stream>>>(x, W_ih, W_hh, b_ih, b_hh, ring);
    ffn_kernel<<<128, 256, 0, stream>>>(ring, W1, b1, W2, partials);
    out_kernel<<<1, 128, 0, stream>>>(partials, b2, out);
}

// Round 5
// 30212.402 us; speedup vs baseline: 5.5291x; 5.5291x over previous
//
#include <hip/hip_runtime.h>
#include <cstdint>

// Problem constants (from reference): I=256, H=1024, O=1, T=16384
#define I_DIM   256
#define H_DIM   1024
#define T_STEPS 16384
#define NBLK    128     // persistent blocks, 1 per CU (256 CUs -> 2x residency margin)
#define CELLS   8       // h cells per block  (128*8 = 1024)
#define THREADS 512     // 8 waves; wave wv owns cell wv; 16-lane group = gate

// Fast device math: v_exp_f32 / v_rcp_f32 based, ~1-2 ulp (validated R3/R4:
// absmax vs numpy ref = 0.0 at the harness's print precision).
__device__ __forceinline__ float fast_sigmoid(float x) {
    return __builtin_amdgcn_rcpf(1.f + __expf(-x));
}
__device__ __forceinline__ float fast_tanh(float x) {
    const float a = fabsf(x);
    const float e = __expf(-2.f * a);
    const float t = (1.f - e) * __builtin_amdgcn_rcpf(1.f + e);
    return copysignf(t, x);
}

// ---------------------------------------------------------------------------
// Persistent LSTM scan kernel == R2 structure (34.4 ms floor) verbatim, plus:
//   * fast gate math (independently validated, halves VALU cycles)
//   * publish pinned by a compiler-only memory barrier (no fence instrs)
// Wave wv computes all 4 gate rows of cell (blk*8+wv): 16-lane group q of the
// wave owns gate row q*H + blk*8 + wv. Gates gathered with in-wave __shfl.
// h broadcast via a 2-slot global ring of (tag<<32 | float_bits) u64 words,
// agent-scope RELAXED atomics (data IS the flag; no fences anywhere).
// ---------------------------------------------------------------------------
__launch_bounds__(THREADS, 2)
__global__ void lstm_persist(const float* __restrict__ x,
                             const float* __restrict__ W_ih,
                             const float* __restrict__ W_hh,
                             const float* __restrict__ b_ih,
                             const float* __restrict__ b_hh,
                             unsigned long long* __restrict__ ring)
{
    __shared__ __align__(16) float h_cur[H_DIM];
    __shared__ __align__(16) float xbuf[2][I_DIM];

    const int tid = threadIdx.x;
    const int blk = blockIdx.x;
    const int wv  = tid >> 6;           // wave id = cell within block (0..7)
    const int q   = (tid >> 4) & 3;     // 16-lane group = gate (i,f,g,o)
    const int l   = tid & 15;           // lane within group
    const int row_g = q * H_DIM + blk * CELLS + wv;   // global gate row

    // --- W_hh row slice into registers: lane l covers k = jj*64 + l*4
    float4 w4[16];
    {
        const float4* Wrow = reinterpret_cast<const float4*>(W_hh + (size_t)row_g * H_DIM);
        #pragma unroll
        for (int jj = 0; jj < 16; ++jj) w4[jj] = Wrow[jj * 16 + l];
    }
    // --- W_ih row slice: lane l covers k = s*64 + l*4  (conflict-free LDS reads)
    float4 wih4[4];
    {
        const float4* Wrow = reinterpret_cast<const float4*>(W_ih + (size_t)row_g * I_DIM);
        #pragma unroll
        for (int s = 0; s < 4; ++s) wih4[s] = Wrow[s * 16 + l];
    }
    const float bias_r = b_ih[row_g] + b_hh[row_g];

    // --- x_0 into xbuf[0]
    if (tid < 64)
        *reinterpret_cast<float4*>(&xbuf[0][tid * 4]) =
            *reinterpret_cast<const float4*>(x + tid * 4);
    __syncthreads();

    // xg partial for t=0 (bias folded in on lane 0 of each 16-lane group)
    float xg = (l == 0) ? bias_r : 0.f;
    #pragma unroll
    for (int s = 0; s < 4; ++s) {
        const float4 xv = *reinterpret_cast<const float4*>(&xbuf[0][s * 64 + l * 4]);
        xg += wih4[s].x * xv.x + wih4[s].y * xv.y + wih4[s].z * xv.z + wih4[s].w * xv.w;
    }

    // x_1 into xbuf[1]  (read during t=0 tail, after the t=0 barrier -> safe)
    if (tid < 64)
        *reinterpret_cast<float4*>(&xbuf[1][tid * 4]) =
            *reinterpret_cast<const float4*>(x + I_DIM + tid * 4);
    int   cur     = 1;      // xbuf[cur] holds x_{t+1}
    float c_state = 0.f;    // cell state (replicated across the wave's 64 lanes)

    for (int t = 0; t < T_STEPS; ++t) {
        // (1) prefetch x_{t+2} into registers (off critical path)
        float4 xpre;
        if (tid < 64) {
            const int tt = (t + 2 < T_STEPS) ? t + 2 : T_STEPS - 1;
            xpre = *reinterpret_cast<const float4*>(x + (size_t)tt * I_DIM + tid * 4);
        }
        // (2) obtain h_{t-1}: poll own 2 words (tag==t-1 means valid)
        float2 hv;
        if (t == 0) {
            hv.x = 0.f; hv.y = 0.f;
        } else {
            const unsigned long long want = (unsigned long long)(t - 1);
            unsigned long long* p = ring + (((t - 1) & 1) ? H_DIM : 0) + 2 * tid;
            unsigned long long v0 = 0, v1 = 0;
            bool g0 = false, g1 = false;
            do {
                if (!g0) { v0 = __hip_atomic_load(p,     __ATOMIC_RELAXED, __HIP_MEMORY_SCOPE_AGENT); g0 = ((v0 >> 32) == want); }
                if (!g1) { v1 = __hip_atomic_load(p + 1, __ATOMIC_RELAXED, __HIP_MEMORY_SCOPE_AGENT); g1 = ((v1 >> 32) == want); }
            } while (!(g0 && g1));
            hv.x = __uint_as_float((unsigned)v0);
            hv.y = __uint_as_float((unsigned)v1);
        }
        *reinterpret_cast<float2*>(&h_cur[2 * tid]) = hv;
        __syncthreads();

        // (3) recurrent dot: acc = xg_t + W_hh[row,:] . h_{t-1}
        float acc = xg;
        #pragma unroll
        for (int jj = 0; jj < 16; ++jj) {
            const float4 h4 = *reinterpret_cast<const float4*>(&h_cur[jj * 64 + l * 4]);
            acc += w4[jj].x * h4.x + w4[jj].y * h4.y + w4[jj].z * h4.z + w4[jj].w * h4.w;
        }
        // (4) 16-lane butterfly -> row value uniform in each 16-lane group
        acc += __shfl_xor(acc, 1);
        acc += __shfl_xor(acc, 2);
        acc += __shfl_xor(acc, 4);
        acc += __shfl_xor(acc, 8);
        // (5) gather the 4 gate rows of this wave's cell (in-wave, no barrier)
        const float gi_r = __shfl(acc, 0);
        const float gf_r = __shfl(acc, 16);
        const float gg_r = __shfl(acc, 32);
        const float go_r = __shfl(acc, 48);
        // (6) gate nonlinearities (fast math; redundant on all 64 lanes)
        const float gi = fast_sigmoid(gi_r);
        const float gf = fast_sigmoid(gf_r);
        const float gg = fast_tanh(gg_r);
        const float go = fast_sigmoid(go_r);
        c_state = gf * c_state + gi * gg;
        const float h_new = go * fast_tanh(c_state);
        // (7) publish h_t ASAP (lane 0 of each wave), pinned: nothing below
        //     may be scheduled above this store.
        if ((tid & 63) == 0) {
            const unsigned long long pack =
                ((unsigned long long)t << 32) | (unsigned long long)__float_as_uint(h_new);
            __hip_atomic_store(ring + ((t & 1) ? H_DIM : 0) + blk * CELLS + wv, pack,
                               __ATOMIC_RELAXED, __HIP_MEMORY_SCOPE_AGENT);
        }
        asm volatile("" ::: "memory");

        // (8) off-critical-path: xg for t+1, rotate x double-buffer
        float xg_n = (l == 0) ? bias_r : 0.f;
        #pragma unroll
        for (int s = 0; s < 4; ++s) {
            const float4 xv = *reinterpret_cast<const float4*>(&xbuf[cur][s * 64 + l * 4]);
            xg_n += wih4[s].x * xv.x + wih4[s].y * xv.y + wih4[s].z * xv.z + wih4[s].w * xv.w;
        }
        xg = xg_n;
        __syncthreads();   // protects h_cur reuse + xbuf rotation (R2 structure)
        if (tid < 64)
            *reinterpret_cast<float4*>(&xbuf[cur ^ 1][tid * 4]) = xpre;
        cur ^= 1;
    }
}

// ---------------------------------------------------------------------------
// Final FFN: z = relu(h @ W1.T + b1);  partial_b = sum_j z_j * W2_j per block
// ---------------------------------------------------------------------------
__global__ void ffn_kernel(const unsigned long long* __restrict__ ring,
                           const float* __restrict__ W1,
                           const float* __restrict__ b1,
                           const float* __restrict__ W2,
                           float* __restrict__ partials)
{
    __shared__ float psum[8];
    const int tid = threadIdx.x;        // 256
    const int r2  = tid >> 5;           // 0..7
    const int l2  = tid & 31;
    const int j   = blockIdx.x * 8 + r2;
    const unsigned long long* hslot = ring + (((T_STEPS - 1) & 1) ? H_DIM : 0);

    float acc = 0.f;
    #pragma unroll 8
    for (int kk = 0; kk < 32; ++kk) {
        const int   k  = kk * 32 + l2;
        const float hk = __uint_as_float((unsigned)hslot[k]);
        acc += hk * W1[(size_t)j * H_DIM + k];
    }
    acc += __shfl_xor(acc, 1);
    acc += __shfl_xor(acc, 2);
    acc += __shfl_xor(acc, 4);
    acc += __shfl_xor(acc, 8);
    acc += __shfl_xor(acc, 16);
    if (l2 == 0) {
        float z = acc + b1[j];
        z = z > 0.f ? z : 0.f;
        psum[r2] = z * W2[j];
    }
    __syncthreads();
    if (tid == 0) {
        float s = 0.f;
        #pragma unroll
        for (int i = 0; i < 8; ++i) s += psum[i];
        partials[blockIdx.x] = s;
    }
}

__global__ void out_kernel(const float* __restrict__ partials,
                           const float* __restrict__ b2,
                           float* __restrict__ out)
{
    __shared__ float ws2[2];
    const int tid = threadIdx.x;        // 128
    float v = partials[tid];
    v += __shfl_xor(v, 1);
    v += __shfl_xor(v, 2);
    v += __shfl_xor(v, 4);
    v += __shfl_xor(v, 8);
    v += __shfl_xor(v, 16);
    v += __shfl_xor(v, 32);
    if ((tid & 63) == 0) ws2[tid >> 6] = v;
    __syncthreads();
    if (tid == 0) out[0] = ws2[0] + ws2[1] + b2[0];
}

extern "C" void kernel_launch(void* const* d_in, const int* in_sizes, int n_in,
                              void* d_out, int out_size, void* d_ws, size_t ws_size,
                              hipStream_t stream)
{
    const float* x    = (const float*)d_in[0];   // (1,T,I)
    const float* W_ih = (const float*)d_in[1];   // (4H,I)
    const float* W_hh = (const float*)d_in[2];   // (4H,H)
    const float* b_ih = (const float*)d_in[3];   // (4H)
    const float* b_hh = (const float*)d_in[4];   // (4H)
    const float* W1   = (const float*)d_in[5];   // (H,H)
    const float* b1   = (const float*)d_in[6];   // (H)
    const float* W2   = (const float*)d_in[7];   // (1,H)
    const float* b2   = (const float*)d_in[8];   // (1)
    float* out = (float*)d_out;

    unsigned long long* ring = (unsigned long long*)d_ws;         // 2*H u64 = 16 KiB
    const size_t ring_bytes = (size_t)2 * H_DIM * sizeof(unsigned long long);
    float* partials = (float*)((char*)d_ws + ring_bytes);         // 128 f32

    // Poison ring tags so stale tags from a previous replay can never match
    // (tag 0xAAAAAAAA != any step index). Harness also poisons ws to 0xAA.
    hipMemsetAsync(d_ws, 0xAA, ring_bytes, stream);

    lstm_persist<<<NBLK, THREADS, 0, stream>>>(x, W_ih, W_hh, b_ih, b_hh, ring);
    ffn_kernel<<<128, 256, 0, stream>>>(ring, W1, b1, W2, partials);
    out_kernel<<<1, 128, 0, stream>>>(partials, b2, out);
}